// Round 20
// baseline (81.696 us; speedup 1.0000x reference)
//
#include <hip/hip_runtime.h>
#include <hip/hip_bf16.h>

#define BATCH 8192
#define DIN   4096
#define H1    128
#define NLAT  512
#define LAT   32
#define BM    32
#define PP    130           // pacc pitch (ushorts)
#define ZSP   40            // zs pitch (ushorts): 80B rows, 16B-aligned

typedef short bf16x8 __attribute__((ext_vector_type(8)));
typedef short bf16x4 __attribute__((ext_vector_type(4)));
typedef float f32x4  __attribute__((ext_vector_type(4)));
typedef float f32x16 __attribute__((ext_vector_type(16)));

static __device__ __forceinline__ unsigned short f2bf(float f) {
  __hip_bfloat16 h = __float2bfloat16(f);   // native RNE (v_cvt_pk_bf16_f32)
  return *reinterpret_cast<unsigned short*>(&h);
}
static __device__ __forceinline__ float bf2f(unsigned short u) {
  union { unsigned u; float f; } v; v.u = ((unsigned)u) << 16; return v.f;
}

// ---- prep_all: byte-identical to R19. ----
__global__ void prep_all(const float* __restrict__ W1, const float* __restrict__ W2,
                         const float* __restrict__ dec,
                         unsigned short* __restrict__ W1B,
                         unsigned short* __restrict__ W2B,
                         unsigned short* __restrict__ decB) {
  int b = blockIdx.x;
  int t = threadIdx.x;
  int lane = t & 63;
  if (b < 256) {
    int g = lane >> 4, fr = lane & 15;
    int gi = (b << 2) + (t >> 6);
    int kb = ((gi >> 3) << 5) + (g << 3);
    int c = ((gi & 7) << 4) + fr;
    union { bf16x8 v; unsigned short u[8]; } o;
#pragma unroll
    for (int j = 0; j < 8; j++) o.u[j] = f2bf(W1[(size_t)(kb + j) * H1 + c]);
    *(bf16x8*)(W1B + (((size_t)gi << 6) + lane) * 8) = o.v;
  } else if (b < 288) {
    int g = lane >> 4, fr = lane & 15;
    int gi = ((b - 256) << 2) + (t >> 6);
    int kb = ((gi >> 5) << 5) + (g << 3);
    int c = ((gi & 31) << 4) + fr;
    union { bf16x8 v; unsigned short u[8]; } o;
#pragma unroll
    for (int j = 0; j < 8; j++) o.u[j] = f2bf(W2[(size_t)(kb + j) * NLAT + c]);
    *(bf16x8*)(W2B + (((size_t)gi << 6) + lane) * 8) = o.v;
  } else {
    int grp = ((b - 288) << 2) + (t >> 6);
    int cf = grp >> 1, q = grp & 1;
    int m = lane & 31, h = lane >> 5;
    const float* src = dec + ((size_t)(cf * 32 + m)) * LAT + q * 16 + h * 8;
    union { bf16x8 v; unsigned short u[8]; } o;
#pragma unroll
    for (int j = 0; j < 8; j++) o.u[j] = f2bf(src[j]);
    *(bf16x8*)(decB + (((size_t)grp << 6) + lane) * 8) = o.v;
  }
}

// ---- fused_kernel: R19 enc (BM=32, 16 waves/CU, reg-direct barrier-free
// phase A, two-stage pacc) + FUSED recon phase. After the zsum reduction,
// zs (bf16 [32][ZSP]) lands in the LDS freed by pacc; each wave then does
// its 32-row x 256-col recon strip with 32x32x16 MFMAs (R17 layout).
// Removes: recon launch boundary, zsumb global roundtrip; adds tail
// overlap (enc-phase blocks and recon-phase blocks co-exist device-wide). ----
__global__ __launch_bounds__(1024, 4) void fused_kernel(
    const float* __restrict__ x, const unsigned short* __restrict__ W1B,
    const unsigned short* __restrict__ W2B,
    const float* __restrict__ b1, const float* __restrict__ b2,
    const unsigned short* __restrict__ decB,
    float* __restrict__ zout, float* __restrict__ rout) {
  // [0, 66560): pacc bf16 [8][32][PP]       (dies after hs built)
  // [66560, 74752): hs bf16 [32][128] XOR-swizzled
  // zsp f32 [16][16][33] = 33.8 KB aliases [0, 33792)   (phase-B epilogue)
  // zs bf16 [32][ZSP] = 2.5 KB at [33792, 36352)        (recon A operand)
  __shared__ __align__(16) unsigned char smem[74752];
  unsigned short* pacc = (unsigned short*)smem;
  unsigned short* hs   = (unsigned short*)(smem + 66560);
  float* zsp           = (float*)smem;
  unsigned short* zs   = (unsigned short*)(smem + 33792);

  const int t = threadIdx.x;
  const int rbase = blockIdx.x << 5;
  const int w = t >> 6, lane = t & 63;
  const int g = lane >> 4, fr = lane & 15;

  // ---- phase A: reg-direct, barrier-free. Wave w: K in [w*256, +256). ----
  f32x4 acc0[8], acc1[8];
#pragma unroll
  for (int i = 0; i < 8; i++) {
    acc0[i] = (f32x4){0.f, 0.f, 0.f, 0.f};
    acc1[i] = (f32x4){0.f, 0.f, 0.f, 0.f};
  }
  const float* arow0 = x + (size_t)(rbase + fr) * DIN + (w << 8) + (g << 3);
  const float* arow1 = arow0 + ((size_t)DIN << 4);   // +16 rows
#pragma unroll 2
  for (int c = 0; c < 8; ++c) {
    f32x4 a0 = *(const f32x4*)(arow0 + (c << 5));
    f32x4 a1 = *(const f32x4*)(arow0 + (c << 5) + 4);
    f32x4 a2 = *(const f32x4*)(arow1 + (c << 5));
    f32x4 a3 = *(const f32x4*)(arow1 + (c << 5) + 4);
    union { bf16x8 v; unsigned short u[8]; } af0, af1;
#pragma unroll
    for (int j = 0; j < 4; j++) {
      af0.u[j] = f2bf(a0[j]); af0.u[4 + j] = f2bf(a1[j]);
      af1.u[j] = f2bf(a2[j]); af1.u[4 + j] = f2bf(a3[j]);
    }
    const unsigned short* bp =
        W1B + (((size_t)((((w << 3) + c) << 3))) << 9) + (lane << 3);
#pragma unroll
    for (int cf = 0; cf < 8; ++cf) {
      bf16x8 bv = *(const bf16x8*)(bp + ((size_t)cf << 9));
      acc0[cf] = __builtin_amdgcn_mfma_f32_16x16x32_bf16(af0.v, bv, acc0[cf], 0, 0, 0);
      acc1[cf] = __builtin_amdgcn_mfma_f32_16x16x32_bf16(af1.v, bv, acc1[cf], 0, 0, 0);
    }
  }

  // two-stage partial reduction. C/D: col=fr, row=g*4+j.
  const int ws = w & 7;
  if (w < 8) {
#pragma unroll
    for (int cf = 0; cf < 8; ++cf)
#pragma unroll
      for (int j = 0; j < 4; ++j) {
        pacc[(ws * BM + (g << 2) + j) * PP + (cf << 4) + fr] = f2bf(acc0[cf][j]);
        pacc[(ws * BM + 16 + (g << 2) + j) * PP + (cf << 4) + fr] = f2bf(acc1[cf][j]);
      }
  }
  __syncthreads();
  if (w >= 8) {
#pragma unroll
    for (int cf = 0; cf < 8; ++cf)
#pragma unroll
      for (int j = 0; j < 4; ++j) {
        unsigned short* p0 = &pacc[(ws * BM + (g << 2) + j) * PP + (cf << 4) + fr];
        unsigned short* p1 = &pacc[(ws * BM + 16 + (g << 2) + j) * PP + (cf << 4) + fr];
        *p0 = f2bf(bf2f(*p0) + acc0[cf][j]);
        *p1 = f2bf(bf2f(*p1) + acc1[cf][j]);
      }
  }
  __syncthreads();

  // reduce 8 slots + b1 + relu -> hs (bf16, XOR-swizzled 8-granules).
  {
    const int r = t >> 5, c4 = (t & 31) << 2;
    float s0 = b1[c4], s1 = b1[c4 + 1], s2 = b1[c4 + 2], s3 = b1[c4 + 3];
#pragma unroll
    for (int wv = 0; wv < 8; ++wv) {
      union { bf16x4 v; unsigned short u[4]; } p;
      p.v = *(const bf16x4*)&pacc[(wv * BM + r) * PP + c4];
      s0 += bf2f(p.u[0]); s1 += bf2f(p.u[1]); s2 += bf2f(p.u[2]); s3 += bf2f(p.u[3]);
    }
    union { bf16x4 v; unsigned short u[4]; } o;
    o.u[0] = f2bf(fmaxf(s0, 0.f)); o.u[1] = f2bf(fmaxf(s1, 0.f));
    o.u[2] = f2bf(fmaxf(s2, 0.f)); o.u[3] = f2bf(fmaxf(s3, 0.f));
    const int gi = c4 >> 3;
    *(bf16x4*)(hs + (r << 7) + ((gi ^ (r & 15)) << 3) + (c4 & 7)) = o.v;
  }
  __syncthreads();

  // ---- phase B: z = h@W2+b2. Wave (wr=w&1, wc=w>>1): rows wr*16..+16,
  // cols wc*64..+64 (cf = wc*4 + cc). ----
  const int wr = w & 1, wc = w >> 1;
  f32x4 acc2[4];
#pragma unroll
  for (int i = 0; i < 4; i++) acc2[i] = (f32x4){0.f, 0.f, 0.f, 0.f};
#pragma unroll
  for (int k32 = 0; k32 < 4; ++k32) {
    bf16x8 a0 = *(const bf16x8*)(hs + (((wr << 4) + fr) << 7) +
                  ((((k32 << 2) + g) ^ fr) << 3));
#pragma unroll
    for (int cc = 0; cc < 4; ++cc) {
      bf16x8 bv = *(const bf16x8*)(W2B +
          (((size_t)((k32 << 5) + (wc << 2) + cc)) << 9) + (lane << 3));
      acc2[cc] = __builtin_amdgcn_mfma_f32_16x16x32_bf16(a0, bv, acc2[cc], 0, 0, 0);
    }
  }
  // z write + zsum fold. col = wc*64+cc*16+fr; latent=(cc&1)*16+fr.
  {
    f32x4 zv[4];
#pragma unroll
    for (int cc = 0; cc < 4; ++cc) {
      const float b2v = b2[(wc << 6) + (cc << 4) + fr];
#pragma unroll
      for (int j = 0; j < 4; j++) zv[cc][j] = acc2[cc][j] + b2v;
    }
    const int row0 = g << 2;
#pragma unroll
    for (int j = 0; j < 4; j++) {
      const int grow = rbase + (wr << 4) + row0 + j;
#pragma unroll
      for (int cc = 0; cc < 4; ++cc)
        zout[(size_t)grow * NLAT + (wc << 6) + (cc << 4) + fr] = zv[cc][j];
      zsp[(w * 16 + row0 + j) * 33 + fr]      = zv[0][j] + zv[2][j];
      zsp[(w * 16 + row0 + j) * 33 + 16 + fr] = zv[1][j] + zv[3][j];
    }
  }
  __syncthreads();
  // reduce 8 col-wave partials per row-half -> zs LDS (bf16, pitch ZSP)
  {
    const int r = t >> 5, l = t & 31;
    const int rh = r >> 4;
    float s = 0.f;
#pragma unroll
    for (int wcv = 0; wcv < 8; ++wcv)
      s += zsp[((((wcv << 1) | rh) << 4) + (r & 15)) * 33 + l];
    zs[r * ZSP + l] = f2bf(s);
  }
  __syncthreads();

  // ---- phase C (fused recon): wave w -> col-frags cf = w*8..+8
  // (32 cols each). A-frags from zs; 32x32x16 MFMA x2 per frag.
  // C/D: col=lane&31, row=(reg&3)+8*(reg>>2)+4*(lane>>5). ----
  {
    const int m = lane & 31, h = lane >> 5;
    bf16x8 a0 = *(const bf16x8*)(zs + m * ZSP + (h << 3));        // k = h*8+j
    bf16x8 a1 = *(const bf16x8*)(zs + m * ZSP + 16 + (h << 3));   // k = 16+h*8+j
#pragma unroll 2
    for (int f = 0; f < 8; ++f) {
      const int cf = (w << 3) + f;
      bf16x8 bv0 = *(const bf16x8*)(decB + ((size_t)cf << 10) + (lane << 3));
      bf16x8 bv1 = *(const bf16x8*)(decB + ((size_t)cf << 10) + 512 + (lane << 3));
      f32x16 c;
#pragma unroll
      for (int i = 0; i < 16; ++i) c[i] = 0.f;
      c = __builtin_amdgcn_mfma_f32_32x32x16_bf16(a0, bv0, c, 0, 0, 0);
      c = __builtin_amdgcn_mfma_f32_32x32x16_bf16(a1, bv1, c, 0, 0, 0);
      const int colbase = (cf << 5) + m;
#pragma unroll
      for (int r = 0; r < 16; ++r) {
        const int row = rbase + (r & 3) + ((r >> 2) << 3) + (h << 2);
        rout[(size_t)row * DIN + colbase] = c[r];
      }
    }
  }
}

extern "C" void kernel_launch(void* const* d_in, const int* in_sizes, int n_in,
                              void* d_out, int out_size, void* d_ws, size_t ws_size,
                              hipStream_t stream) {
  const float* x   = (const float*)d_in[0];
  const float* W1  = (const float*)d_in[1];
  const float* b1  = (const float*)d_in[2];
  const float* W2  = (const float*)d_in[3];
  const float* b2  = (const float*)d_in[4];
  const float* dec = (const float*)d_in[5];
  float* zout = (float*)d_out;
  float* rout = zout + (size_t)BATCH * NLAT;

  char* ws = (char*)d_ws;
  unsigned short* W1B  = (unsigned short*)ws;                               // 1 MB
  unsigned short* W2B  = (unsigned short*)(ws + (1u << 20));                // 128 KB
  unsigned short* decB = (unsigned short*)(ws + (1u << 20) + (128u << 10)); // 256 KB

  prep_all<<<dim3(352), 256, 0, stream>>>(W1, W2, dec, W1B, W2B, decB);
  fused_kernel<<<dim3(BATCH / BM), 1024, 0, stream>>>(x, W1B, W2B, b1, b2, decB, zout, rout);
}

// Round 21
// 76.281 us; speedup vs baseline: 1.0710x; 1.0710x over previous
//
#include <hip/hip_runtime.h>
#include <hip/hip_bf16.h>

#define BATCH 8192
#define DIN   4096
#define H1    128
#define NLAT  512
#define LAT   32
#define BM    32
#define PP    130           // pacc pitch (ushorts)

typedef short bf16x8 __attribute__((ext_vector_type(8)));
typedef short bf16x4 __attribute__((ext_vector_type(4)));
typedef float f32x4  __attribute__((ext_vector_type(4)));
typedef float f32x16 __attribute__((ext_vector_type(16)));

static __device__ __forceinline__ unsigned short f2bf(float f) {
  __hip_bfloat16 h = __float2bfloat16(f);   // native RNE; compiler fuses to v_cvt_pk_bf16_f32
  return *reinterpret_cast<unsigned short*>(&h);
}
static __device__ __forceinline__ float bf2f(unsigned short u) {
  union { unsigned u; float f; } v; v.u = ((unsigned)u) << 16; return v.f;
}

// ---- prep_all: byte-identical to R19. ----
__global__ void prep_all(const float* __restrict__ W1, const float* __restrict__ W2,
                         const float* __restrict__ dec,
                         unsigned short* __restrict__ W1B,
                         unsigned short* __restrict__ W2B,
                         unsigned short* __restrict__ decB) {
  int b = blockIdx.x;
  int t = threadIdx.x;
  int lane = t & 63;
  if (b < 256) {
    int g = lane >> 4, fr = lane & 15;
    int gi = (b << 2) + (t >> 6);
    int kb = ((gi >> 3) << 5) + (g << 3);
    int c = ((gi & 7) << 4) + fr;
    union { bf16x8 v; unsigned short u[8]; } o;
#pragma unroll
    for (int j = 0; j < 8; j++) o.u[j] = f2bf(W1[(size_t)(kb + j) * H1 + c]);
    *(bf16x8*)(W1B + (((size_t)gi << 6) + lane) * 8) = o.v;
  } else if (b < 288) {
    int g = lane >> 4, fr = lane & 15;
    int gi = ((b - 256) << 2) + (t >> 6);
    int kb = ((gi >> 5) << 5) + (g << 3);
    int c = ((gi & 31) << 4) + fr;
    union { bf16x8 v; unsigned short u[8]; } o;
#pragma unroll
    for (int j = 0; j < 8; j++) o.u[j] = f2bf(W2[(size_t)(kb + j) * NLAT + c]);
    *(bf16x8*)(W2B + (((size_t)gi << 6) + lane) * 8) = o.v;
  } else {
    int grp = ((b - 288) << 2) + (t >> 6);
    int cf = grp >> 1, q = grp & 1;
    int m = lane & 31, h = lane >> 5;
    const float* src = dec + ((size_t)(cf * 32 + m)) * LAT + q * 16 + h * 8;
    union { bf16x8 v; unsigned short u[8]; } o;
#pragma unroll
    for (int j = 0; j < 8; j++) o.u[j] = f2bf(src[j]);
    *(bf16x8*)(decB + (((size_t)grp << 6) + lane) * 8) = o.v;
  }
}

// ---- enc_kernel: byte-identical to R19 (BM=32 rows/wave x 16 waves/CU,
// reg-direct barrier-free phase A, two-stage pacc, native cvt_pk).
// Measured composition: enc ~38us of the 77.8us total. ----
__global__ __launch_bounds__(1024, 4) void enc_kernel(
    const float* __restrict__ x, const unsigned short* __restrict__ W1B,
    const unsigned short* __restrict__ W2B,
    const float* __restrict__ b1, const float* __restrict__ b2,
    float* __restrict__ zout, unsigned short* __restrict__ zsumb) {
  // [0, 66560): pacc bf16 [8][32][PP]   (dies after hs built)
  // [66560, 74752): hs bf16 [32][128] XOR-swizzled
  // zsp f32 [16][16][33] = 33.8 KB aliases [0, 33792)
  __shared__ __align__(16) unsigned char smem[74752];
  unsigned short* pacc = (unsigned short*)smem;
  unsigned short* hs   = (unsigned short*)(smem + 66560);
  float* zsp           = (float*)smem;

  const int t = threadIdx.x;
  const int rbase = blockIdx.x << 5;
  const int w = t >> 6, lane = t & 63;
  const int g = lane >> 4, fr = lane & 15;

  // ---- phase A: reg-direct, barrier-free. Wave w: K in [w*256, +256). ----
  f32x4 acc0[8], acc1[8];
#pragma unroll
  for (int i = 0; i < 8; i++) {
    acc0[i] = (f32x4){0.f, 0.f, 0.f, 0.f};
    acc1[i] = (f32x4){0.f, 0.f, 0.f, 0.f};
  }
  const float* arow0 = x + (size_t)(rbase + fr) * DIN + (w << 8) + (g << 3);
  const float* arow1 = arow0 + ((size_t)DIN << 4);   // +16 rows
#pragma unroll 2
  for (int c = 0; c < 8; ++c) {
    f32x4 a0 = *(const f32x4*)(arow0 + (c << 5));
    f32x4 a1 = *(const f32x4*)(arow0 + (c << 5) + 4);
    f32x4 a2 = *(const f32x4*)(arow1 + (c << 5));
    f32x4 a3 = *(const f32x4*)(arow1 + (c << 5) + 4);
    union { bf16x8 v; unsigned short u[8]; } af0, af1;
#pragma unroll
    for (int j = 0; j < 4; j++) {
      af0.u[j] = f2bf(a0[j]); af0.u[4 + j] = f2bf(a1[j]);
      af1.u[j] = f2bf(a2[j]); af1.u[4 + j] = f2bf(a3[j]);
    }
    const unsigned short* bp =
        W1B + (((size_t)((((w << 3) + c) << 3))) << 9) + (lane << 3);
#pragma unroll
    for (int cf = 0; cf < 8; ++cf) {
      bf16x8 bv = *(const bf16x8*)(bp + ((size_t)cf << 9));
      acc0[cf] = __builtin_amdgcn_mfma_f32_16x16x32_bf16(af0.v, bv, acc0[cf], 0, 0, 0);
      acc1[cf] = __builtin_amdgcn_mfma_f32_16x16x32_bf16(af1.v, bv, acc1[cf], 0, 0, 0);
    }
  }

  // two-stage partial reduction. C/D: col=fr, row=g*4+j.
  const int ws = w & 7;
  if (w < 8) {
#pragma unroll
    for (int cf = 0; cf < 8; ++cf)
#pragma unroll
      for (int j = 0; j < 4; ++j) {
        pacc[(ws * BM + (g << 2) + j) * PP + (cf << 4) + fr] = f2bf(acc0[cf][j]);
        pacc[(ws * BM + 16 + (g << 2) + j) * PP + (cf << 4) + fr] = f2bf(acc1[cf][j]);
      }
  }
  __syncthreads();
  if (w >= 8) {
#pragma unroll
    for (int cf = 0; cf < 8; ++cf)
#pragma unroll
      for (int j = 0; j < 4; ++j) {
        unsigned short* p0 = &pacc[(ws * BM + (g << 2) + j) * PP + (cf << 4) + fr];
        unsigned short* p1 = &pacc[(ws * BM + 16 + (g << 2) + j) * PP + (cf << 4) + fr];
        *p0 = f2bf(bf2f(*p0) + acc0[cf][j]);
        *p1 = f2bf(bf2f(*p1) + acc1[cf][j]);
      }
  }
  __syncthreads();

  // reduce 8 slots + b1 + relu -> hs (bf16, XOR-swizzled 8-granules).
  // 1024 thr: 32/row, 4 cols each.
  {
    const int r = t >> 5, c4 = (t & 31) << 2;
    float s0 = b1[c4], s1 = b1[c4 + 1], s2 = b1[c4 + 2], s3 = b1[c4 + 3];
#pragma unroll
    for (int wv = 0; wv < 8; ++wv) {
      union { bf16x4 v; unsigned short u[4]; } p;
      p.v = *(const bf16x4*)&pacc[(wv * BM + r) * PP + c4];
      s0 += bf2f(p.u[0]); s1 += bf2f(p.u[1]); s2 += bf2f(p.u[2]); s3 += bf2f(p.u[3]);
    }
    union { bf16x4 v; unsigned short u[4]; } o;
    o.u[0] = f2bf(fmaxf(s0, 0.f)); o.u[1] = f2bf(fmaxf(s1, 0.f));
    o.u[2] = f2bf(fmaxf(s2, 0.f)); o.u[3] = f2bf(fmaxf(s3, 0.f));
    const int gi = c4 >> 3;
    *(bf16x4*)(hs + (r << 7) + ((gi ^ (r & 15)) << 3) + (c4 & 7)) = o.v;
  }
  __syncthreads();

  // ---- phase B: z = h@W2+b2. Wave (wr=w&1, wc=w>>1): rows wr*16..+16,
  // cols wc*64..+64 (cf = wc*4 + cc). ----
  const int wr = w & 1, wc = w >> 1;
  f32x4 acc2[4];
#pragma unroll
  for (int i = 0; i < 4; i++) acc2[i] = (f32x4){0.f, 0.f, 0.f, 0.f};
#pragma unroll
  for (int k32 = 0; k32 < 4; ++k32) {
    bf16x8 a0 = *(const bf16x8*)(hs + (((wr << 4) + fr) << 7) +
                  ((((k32 << 2) + g) ^ fr) << 3));
#pragma unroll
    for (int cc = 0; cc < 4; ++cc) {
      bf16x8 bv = *(const bf16x8*)(W2B +
          (((size_t)((k32 << 5) + (wc << 2) + cc)) << 9) + (lane << 3));
      acc2[cc] = __builtin_amdgcn_mfma_f32_16x16x32_bf16(a0, bv, acc2[cc], 0, 0, 0);
    }
  }
  // z write + zsum fold. col = wc*64+cc*16+fr; latent=(cc&1)*16+fr;
  // cc 0,1 -> factor 2wc; cc 2,3 -> factor 2wc+1.
  {
    f32x4 zv[4];
#pragma unroll
    for (int cc = 0; cc < 4; ++cc) {
      const float b2v = b2[(wc << 6) + (cc << 4) + fr];
#pragma unroll
      for (int j = 0; j < 4; j++) zv[cc][j] = acc2[cc][j] + b2v;
    }
    const int row0 = g << 2;
#pragma unroll
    for (int j = 0; j < 4; j++) {
      const int grow = rbase + (wr << 4) + row0 + j;
#pragma unroll
      for (int cc = 0; cc < 4; ++cc)
        zout[(size_t)grow * NLAT + (wc << 6) + (cc << 4) + fr] = zv[cc][j];
      zsp[(w * 16 + row0 + j) * 33 + fr]      = zv[0][j] + zv[2][j];
      zsp[(w * 16 + row0 + j) * 33 + 16 + fr] = zv[1][j] + zv[3][j];
    }
  }
  __syncthreads();
  // reduce 8 col-wave partials per row-half -> zsumb (1024 thr = 32x32)
  {
    const int r = t >> 5, l = t & 31;
    const int rh = r >> 4;
    float s = 0.f;
#pragma unroll
    for (int wcv = 0; wcv < 8; ++wcv)
      s += zsp[((((wcv << 1) | rh) << 4) + (r & 15)) * 33 + l];
    zsumb[(size_t)(rbase + r) * LAT + l] = f2bf(s);
  }
}

// ---- recon_kernel: byte-identical to R17/R19 (32x32x16 MFMA, measured 20.9us). ----
__global__ __launch_bounds__(256) void recon_kernel(
    const unsigned short* __restrict__ zsumb, const unsigned short* __restrict__ decB,
    float* __restrict__ rout) {
  const int t = threadIdx.x;
  const int w = t >> 6, lane = t & 63;
  const int m = lane & 31, h = lane >> 5;
  const int rbase = (blockIdx.x >> 2) << 5;
  const int cfbase = ((blockIdx.x & 3) << 5) + (w << 3);

  const unsigned short* arow = zsumb + ((size_t)(rbase + m) << 5) + (h << 3);
  bf16x8 a0 = *(const bf16x8*)(arow);
  bf16x8 a1 = *(const bf16x8*)(arow + 16);

#pragma unroll 2
  for (int f = 0; f < 8; ++f) {
    const int cf = cfbase + f;
    bf16x8 bv0 = *(const bf16x8*)(decB + ((size_t)cf << 10) + (lane << 3));
    bf16x8 bv1 = *(const bf16x8*)(decB + ((size_t)cf << 10) + 512 + (lane << 3));
    f32x16 c;
#pragma unroll
    for (int i = 0; i < 16; ++i) c[i] = 0.f;
    c = __builtin_amdgcn_mfma_f32_32x32x16_bf16(a0, bv0, c, 0, 0, 0);
    c = __builtin_amdgcn_mfma_f32_32x32x16_bf16(a1, bv1, c, 0, 0, 0);
    const int colbase = (cf << 5) + m;
#pragma unroll
    for (int r = 0; r < 16; ++r) {
      const int row = rbase + (r & 3) + ((r >> 2) << 3) + (h << 2);
      rout[(size_t)row * DIN + colbase] = c[r];
    }
  }
}

extern "C" void kernel_launch(void* const* d_in, const int* in_sizes, int n_in,
                              void* d_out, int out_size, void* d_ws, size_t ws_size,
                              hipStream_t stream) {
  const float* x   = (const float*)d_in[0];
  const float* W1  = (const float*)d_in[1];
  const float* b1  = (const float*)d_in[2];
  const float* W2  = (const float*)d_in[3];
  const float* b2  = (const float*)d_in[4];
  const float* dec = (const float*)d_in[5];
  float* zout = (float*)d_out;
  float* rout = zout + (size_t)BATCH * NLAT;

  char* ws = (char*)d_ws;
  unsigned short* W1B   = (unsigned short*)ws;                               // 1 MB
  unsigned short* W2B   = (unsigned short*)(ws + (1u << 20));                // 128 KB
  unsigned short* decB  = (unsigned short*)(ws + (1u << 20) + (128u << 10)); // 256 KB
  unsigned short* zsumb = (unsigned short*)(ws + (1u << 20) + (384u << 10)); // 512 KB

  prep_all<<<dim3(352), 256, 0, stream>>>(W1, W2, dec, W1B, W2B, decB);
  enc_kernel<<<dim3(BATCH / BM), 1024, 0, stream>>>(x, W1B, W2B, b1, b2, zout, zsumb);
  recon_kernel<<<dim3(1024), 256, 0, stream>>>(zsumb, decB, rout);
}